// Round 11
// baseline (628.387 us; speedup 1.0000x reference)
//
#include <hip/hip_runtime.h>
#include <cstdint>
#include <cstddef>

#define EPSF 1e-9f

typedef __bf16 bf16x8 __attribute__((ext_vector_type(8)));
typedef float fvec4 __attribute__((ext_vector_type(4)));

__device__ __forceinline__ float blo(unsigned int u) { return __uint_as_float(u << 16); }
__device__ __forceinline__ float bhi(unsigned int u) { return __uint_as_float(u & 0xffff0000u); }
__device__ __forceinline__ unsigned short f2bf(float f) {
  unsigned int u = __float_as_uint(f);
  u += 0x7fffu + ((u >> 16) & 1u);
  return (unsigned short)(u >> 16);
}
__device__ __forceinline__ unsigned int pack2bf(float a, float b) {
  return (unsigned int)f2bf(a) | ((unsigned int)f2bf(b) << 16);
}

// ---------------- zero ----------------
__global__ __launch_bounds__(256) void fzero(float* __restrict__ p, long n) {
  long i = (long)blockIdx.x * blockDim.x + threadIdx.x;
  long stride = (long)gridDim.x * blockDim.x;
  long n4 = n >> 2;
  float4* p4 = (float4*)p;
  for (long j = i; j < n4; j += stride) p4[j] = make_float4(0.f, 0.f, 0.f, 0.f);
  for (long j = (n4 << 2) + i; j < n; j += stride) p[j] = 0.f;
}

// ---- fold rel_att/rel_msg into Wk/Wv -> rows 0..255 of WkvqT[t] ([384 cols][128 k], bf16) ----
__global__ __launch_bounds__(256) void fuse_w(
    const float* __restrict__ Wk, const float* __restrict__ bk,
    const float* __restrict__ Wv, const float* __restrict__ bv,
    const float* __restrict__ rel_att, const float* __restrict__ rel_msg,
    __bf16* __restrict__ WkvqT, float* __restrict__ bkvq)
{
  int i = blockIdx.x;   // 0..128 (128 == bias row)
  int t = blockIdx.y;
  int c = threadIdx.x;  // 0..255: [0,128)=k cols, [128,256)=v cols
  int m = c >> 7, cc = c & 127;
  int h = cc >> 4, e = cc & 15;
  const float* R = (m ? rel_msg : rel_att) + t * 2048 + h * 256;
  const float* srcW = (m ? Wv : Wk) + t * 16384;
  const float* srcB = (m ? bv : bk) + t * 128;
  const float* row = (i < 128) ? (srcW + i * 128) : srcB;
  float acc = 0.f;
#pragma unroll
  for (int d = 0; d < 16; ++d) acc = fmaf(row[h * 16 + d], R[d * 16 + e], acc);
  if (i < 128) WkvqT[(size_t)t * 49152 + (size_t)c * 128 + i] = (__bf16)acc;
  else         bkvq[t * 384 + c] = acc;
}

// ---- Wq -> rows 256..383 of WkvqT[t] (+q bias); Wa -> WaT [t][col][k] ----
__global__ __launch_bounds__(128) void cvt_wT(
    const float* __restrict__ Wq, const float* __restrict__ bq,
    const float* __restrict__ Wa,
    __bf16* __restrict__ WkvqT, __bf16* __restrict__ WaT,
    float* __restrict__ bkvq)
{
  int k = blockIdx.x, t = blockIdx.y, c = threadIdx.x;
  if (blockIdx.z == 0) {
    WkvqT[(size_t)t * 49152 + (size_t)(256 + c) * 128 + k] = (__bf16)Wq[t * 16384 + k * 128 + c];
    if (k == 0) bkvq[t * 384 + 256 + c] = bq[t * 128 + c];
  } else {
    WaT[(size_t)t * 16384 + (size_t)c * 128 + k] = (__bf16)Wa[t * 16384 + k * 128 + c];
  }
}

// ---------------- persistent double-buffered KVQ MFMA GEMM ----------------
// Grid-stride over 64-row tiles of [A-type | B-type]. Per iter: ds_write staged
// regs -> buf[cur]; ONE barrier; issue next tile's global loads (latency hides
// under compute); compute 3 col-tiles from buf[cur] (swapped mfma -> uint2 stores).
__global__ __launch_bounds__(256, 4) void gemm_kvq(
    const float* __restrict__ Aa, int Ma, const float* __restrict__ Ab, int Mb,
    const __bf16* __restrict__ WTall, const float* __restrict__ ball,
    __bf16* __restrict__ KVa, __bf16* __restrict__ Qa,
    __bf16* __restrict__ KVb, __bf16* __restrict__ Qb,
    int ntile_a, int ntiles)
{
  __shared__ __bf16 As[2][64 * 128];   // 2 x 16 KB, byte ^= (row&7)<<4
  const int tid = threadIdx.x;
  const int l = tid & 63, wid = tid >> 6;
  const int l15 = l & 15, l4 = l >> 4;
  const int wm = wid & 1, wn = wid >> 1;

  float4 st[8];
  auto issue = [&](int tile) {
    const bool isA = tile < ntile_a;
    const float* A = isA ? Aa : Ab;
    const int M = isA ? Ma : Mb;
    const int rowb = (isA ? tile : tile - ntile_a) * 64;
#pragma unroll
    for (int i = 0; i < 4; ++i) {
      int f = tid + i * 256;
      int r = f >> 4, ch = f & 15;
      int gr = rowb + r; gr = gr < M ? gr : M - 1;
      const float4* ap = (const float4*)(A + (size_t)gr * 128 + ch * 8);
      st[2 * i] = ap[0]; st[2 * i + 1] = ap[1];
    }
  };

  int it = blockIdx.x;
  if (it < ntiles) issue(it);
  int cur = 0;
  for (; it < ntiles; it += gridDim.x, cur ^= 1) {
    // write staged regs (current tile) into LDS buf[cur], converted to bf16
#pragma unroll
    for (int i = 0; i < 4; ++i) {
      int f = tid + i * 256;
      int r = f >> 4, ch = f & 15;
      float4 a0 = st[2 * i], a1 = st[2 * i + 1];
      bf16x8 v;
      v[0] = (__bf16)a0.x; v[1] = (__bf16)a0.y; v[2] = (__bf16)a0.z; v[3] = (__bf16)a0.w;
      v[4] = (__bf16)a1.x; v[5] = (__bf16)a1.y; v[6] = (__bf16)a1.z; v[7] = (__bf16)a1.w;
      int sw = (ch * 16) ^ ((r & 7) << 4);
      *(bf16x8*)((char*)As[cur] + r * 256 + sw) = v;
    }
    __syncthreads();                    // the only barrier per iteration

    int nxt = it + gridDim.x;
    if (nxt < ntiles) issue(nxt);       // HBM latency hides under compute below

    const bool isA = it < ntile_a;
    const int M = isA ? Ma : Mb;
    const int rowb = (isA ? it : it - ntile_a) * 64;
    const __bf16* WT = WTall + (isA ? 0 : 49152);
    const float* bs = ball + (isA ? 0 : 384);
    __bf16* KV = isA ? KVa : KVb;
    __bf16* Q  = isA ? Qa : Qb;

    bf16x8 af[2][4];                    // X-frags, reused across 3 col tiles
#pragma unroll
    for (int m = 0; m < 2; ++m)
#pragma unroll
      for (int ks = 0; ks < 4; ++ks) {
        int r = wm * 32 + m * 16 + l15;
        int off = (ks * 64 + l4 * 16) ^ ((r & 7) << 4);
        af[m][ks] = *(const bf16x8*)((const char*)As[cur] + r * 256 + off);
      }

#pragma unroll
    for (int t = 0; t < 3; ++t) {       // tiles 0,1 -> KV; 2 -> Q
      const int colb = t * 128 + wn * 64;
      fvec4 z = {0.f, 0.f, 0.f, 0.f};
      fvec4 acc[2][4];
#pragma unroll
      for (int m = 0; m < 2; ++m)
#pragma unroll
        for (int n = 0; n < 4; ++n) acc[m][n] = z;

      bf16x8 bfr[4][4];
#pragma unroll
      for (int n = 0; n < 4; ++n)
#pragma unroll
        for (int ks = 0; ks < 4; ++ks)
          bfr[n][ks] = *(const bf16x8*)(WT + (size_t)(colb + n * 16 + l15) * 128 + ks * 32 + l4 * 8);

#pragma unroll
      for (int ks = 0; ks < 4; ++ks)
#pragma unroll
        for (int m = 0; m < 2; ++m)
#pragma unroll
          for (int n = 0; n < 4; ++n)   // swapped operands -> transposed fragment
            acc[m][n] = __builtin_amdgcn_mfma_f32_16x16x32_bf16(bfr[n][ks], af[m][ks], acc[m][n], 0, 0, 0);

#pragma unroll
      for (int m = 0; m < 2; ++m) {
        int r = rowb + wm * 32 + m * 16 + l15;
        if (r >= M) continue;
#pragma unroll
        for (int n = 0; n < 4; ++n) {
          int cb = colb + n * 16 + l4 * 4;    // 4 consecutive cols
          fvec4 b4 = *(const fvec4*)(bs + cb);
          uint2 w;
          w.x = pack2bf(acc[m][n][0] + b4[0], acc[m][n][1] + b4[1]);
          w.y = pack2bf(acc[m][n][2] + b4[2], acc[m][n][3] + b4[3]);
          if (t < 2) *(uint2*)(KV + (size_t)r * 256 + cb) = w;
          else       *(uint2*)(Q + (size_t)r * 128 + (cb - 256)) = w;
        }
      }
    }
  }
}

// ---------------- CSR build (both relations concatenated: [NB dsts | NA dsts]) ----------------
__global__ __launch_bounds__(256) void csr_count2(
    const int* __restrict__ dst0, int E0, const int* __restrict__ dst1, int E1,
    int* __restrict__ deg, int NB)
{
  int e = blockIdx.x * 256 + threadIdx.x;
  if (e < E0) atomicAdd(&deg[dst0[e]], 1);
  else if (e < E0 + E1) atomicAdd(&deg[NB + dst1[e - E0]], 1);
}

__global__ __launch_bounds__(256) void csr_partial(
    const int* __restrict__ deg, int N, int* __restrict__ partial)
{
  int base = blockIdx.x * 1024 + threadIdx.x * 4;
  int s = 0;
#pragma unroll
  for (int i = 0; i < 4; ++i) if (base + i < N) s += deg[base + i];
#pragma unroll
  for (int m = 1; m < 64; m <<= 1) s += __shfl_xor(s, m, 64);
  __shared__ int wsum[4];
  if ((threadIdx.x & 63) == 0) wsum[threadIdx.x >> 6] = s;
  __syncthreads();
  if (threadIdx.x == 0) partial[blockIdx.x] = wsum[0] + wsum[1] + wsum[2] + wsum[3];
}

__global__ void csr_scan_partials(const int* __restrict__ partial,
                                  int* __restrict__ pscan, int NP)
{
  if (blockIdx.x == 0 && threadIdx.x == 0) {
    int s = 0;
    for (int i = 0; i < NP; ++i) { pscan[i] = s; s += partial[i]; }
  }
}

__global__ __launch_bounds__(256) void csr_scan_chunk(
    const int* __restrict__ deg, const int* __restrict__ pscan,
    int* __restrict__ row_start, int* __restrict__ cursor, int N)
{
  __shared__ int ls[256];
  int base = blockIdx.x * 1024 + threadIdx.x * 4;
  int v0 = 0, v1 = 0, v2 = 0, v3 = 0;
  if (base + 0 < N) v0 = deg[base + 0];
  if (base + 1 < N) v1 = deg[base + 1];
  if (base + 2 < N) v2 = deg[base + 2];
  if (base + 3 < N) v3 = deg[base + 3];
  int s = v0 + v1 + v2 + v3;
  ls[threadIdx.x] = s;
  __syncthreads();
  for (int off = 1; off < 256; off <<= 1) {
    int t = (threadIdx.x >= off) ? ls[threadIdx.x - off] : 0;
    __syncthreads();
    ls[threadIdx.x] += t;
    __syncthreads();
  }
  int excl = pscan[blockIdx.x] + ls[threadIdx.x] - s;
  int p0 = excl, p1 = excl + v0, p2 = excl + v0 + v1, p3 = excl + v0 + v1 + v2;
  if (base + 0 < N) { row_start[base + 0] = p0; cursor[base + 0] = p0; }
  if (base + 1 < N) { row_start[base + 1] = p1; cursor[base + 1] = p1; }
  if (base + 2 < N) { row_start[base + 2] = p2; cursor[base + 2] = p2; }
  if (base + 3 < N) { row_start[base + 3] = p3; cursor[base + 3] = p3; }
}

__global__ __launch_bounds__(256) void csr_scatter2(
    const int* __restrict__ dst0, const int* __restrict__ src0, const float* __restrict__ ew0, int E0,
    const int* __restrict__ dst1, const int* __restrict__ src1, const float* __restrict__ ew1, int E1,
    int* __restrict__ cursor, int* __restrict__ sidx, float* __restrict__ ewc, int NB)
{
  int e = blockIdx.x * 256 + threadIdx.x;
  if (e < E0) {
    int p = atomicAdd(&cursor[dst0[e]], 1);
    sidx[p] = src0[e];
    ewc[p] = fmaxf(ew0[e], 0.f);
  } else if (e < E0 + E1) {
    int e1 = e - E0;
    int p = atomicAdd(&cursor[NB + dst1[e1]], 1);
    sidx[p] = src1[e1];
    ewc[p] = fmaxf(ew1[e1], 0.f);
  }
}

// ---------------- fused per-dst attention, both relations in one dispatch ----------------
__device__ __forceinline__ void proc_edge(
    float qlo, float qhi, unsigned int ku, unsigned int vu, float w,
    float inv_den, float pr, float& s, float2& acc)
{
  float t = qlo * blo(ku) + qhi * bhi(ku);
  t += __shfl_xor(t, 1, 64);
  t += __shfl_xor(t, 2, 64);
  t += __shfl_xor(t, 4, 64);             // 16-dim head dot broadcast in 8-lane group
  float x = __expf((t + __logf(w * inv_den + EPSF)) * pr);
  s += x;
  acc.x = fmaf(x, blo(vu), acc.x);
  acc.y = fmaf(x, bhi(vu), acc.y);
}

// one 64-lane wave per dst node (global id over [NB|NA]); lane owns 2 dims
__global__ __launch_bounds__(256) void hgt_dst(
    const __bf16* __restrict__ kv0, const __bf16* __restrict__ q0,
    const __bf16* __restrict__ kv1, const __bf16* __restrict__ q1,
    const int* __restrict__ row_start, const int* __restrict__ deg,
    const int* __restrict__ sidx, const float* __restrict__ ewc,
    const float* __restrict__ pri16,
    __bf16* __restrict__ agg0, __bf16* __restrict__ agg1, int NB, int N2)
{
  int n = (blockIdx.x * 256 + threadIdx.x) >> 6;
  int lane = threadIdx.x & 63;
  if (n >= N2) return;
  bool g0 = n < NB;
  int nl = g0 ? n : n - NB;
  const unsigned short* kvs = (const unsigned short*)(g0 ? kv0 : kv1);
  const unsigned short* qrow = (const unsigned short*)(g0 ? q0 : q1) + (size_t)nl * 128;
  const float* pri8 = pri16 + (g0 ? 0 : 8);
  int c0 = lane * 2;
  unsigned int* out = (unsigned int*)((g0 ? agg0 : agg1) + (size_t)nl * 128 + c0);
  int d = deg[n];
  if (d == 0) { out[0] = 0u; return; }
  int base = row_start[n];

  float ds = 0.f;
  for (int j = lane; j < d; j += 64) ds += ewc[base + j];
#pragma unroll
  for (int m = 1; m < 64; m <<= 1) ds += __shfl_xor(ds, m, 64);
  float inv_den = 1.f / fmaxf(ds, EPSF);

  int h = lane >> 3;
  float pr = pri8[h] * 0.25f;            // pri / sqrt(DK)
  unsigned int qu = *(const unsigned int*)(qrow + c0);
  float qlo = blo(qu), qhi = bhi(qu);

  float s = 0.f;
  float2 acc = make_float2(0.f, 0.f);
  int j = 0;
  for (; j + 4 <= d; j += 4) {           // batch 4 edges: 8 gathers in flight
    int b = base + j;
    int si0 = sidx[b], si1 = sidx[b + 1], si2 = sidx[b + 2], si3 = sidx[b + 3];
    float w0 = ewc[b], w1 = ewc[b + 1], w2 = ewc[b + 2], w3 = ewc[b + 3];
    const unsigned short* p0 = kvs + (size_t)si0 * 256 + c0;
    const unsigned short* p1 = kvs + (size_t)si1 * 256 + c0;
    const unsigned short* p2 = kvs + (size_t)si2 * 256 + c0;
    const unsigned short* p3 = kvs + (size_t)si3 * 256 + c0;
    unsigned int k0 = *(const unsigned int*)p0, v0 = *(const unsigned int*)(p0 + 128);
    unsigned int k1 = *(const unsigned int*)p1, v1 = *(const unsigned int*)(p1 + 128);
    unsigned int k2 = *(const unsigned int*)p2, v2 = *(const unsigned int*)(p2 + 128);
    unsigned int k3 = *(const unsigned int*)p3, v3 = *(const unsigned int*)(p3 + 128);
    proc_edge(qlo, qhi, k0, v0, w0, inv_den, pr, s, acc);
    proc_edge(qlo, qhi, k1, v1, w1, inv_den, pr, s, acc);
    proc_edge(qlo, qhi, k2, v2, w2, inv_den, pr, s, acc);
    proc_edge(qlo, qhi, k3, v3, w3, inv_den, pr, s, acc);
  }
  for (; j < d; ++j) {
    int b = base + j;
    const unsigned short* p = kvs + (size_t)sidx[b] * 256 + c0;
    proc_edge(qlo, qhi, *(const unsigned int*)p, *(const unsigned int*)(p + 128),
              ewc[b], inv_den, pr, s, acc);
  }
  float is = 1.f / s;
  out[0] = pack2bf(acc.x * is, acc.y * is);
}

// ---------------- fused Wa-projection + skip-mix + LayerNorm (both types) ----------------
__global__ __launch_bounds__(256) void wa_ln(
    const __bf16* __restrict__ Ag_a, const __bf16* __restrict__ Ag_b,
    const __bf16* __restrict__ WaT, const float* __restrict__ ba,
    const float* __restrict__ x_a, const float* __restrict__ x_b,
    const float* __restrict__ lng, const float* __restrict__ lnb,
    const float* __restrict__ skip, float* __restrict__ out,
    int NA, int NB, int nblk_a)
{
  const int tid = threadIdx.x, l = tid & 63, wid = tid >> 6;
  const int l15 = l & 15, l4 = l >> 4;
  const bool isA = blockIdx.x < (unsigned)nblk_a;
  const int blk = isA ? blockIdx.x : blockIdx.x - nblk_a;
  const int M = isA ? NA : NB;
  const __bf16* Ag = isA ? Ag_a : Ag_b;
  const __bf16* WT = WaT + (isA ? 0 : 16384);
  const float* bias = ba + (isA ? 0 : 128);
  const float* xb = isA ? x_a : x_b;
  const float* g = lng + (isA ? 0 : 128);
  const float* bb = lnb + (isA ? 0 : 128);
  float* o = out + (isA ? (size_t)0 : (size_t)NA * 128);
  const int rowb = blk * 64 + wid * 16;
  const int r = rowb + l15;
  const int rc = r < M ? r : M - 1;

  bf16x8 af[4];
#pragma unroll
  for (int ks = 0; ks < 4; ++ks)
    af[ks] = *(const bf16x8*)(Ag + (size_t)rc * 128 + ks * 32 + l4 * 8);

  fvec4 z = {0.f, 0.f, 0.f, 0.f};
  fvec4 acc[8];
#pragma unroll
  for (int n = 0; n < 8; ++n) acc[n] = z;
#pragma unroll
  for (int ks = 0; ks < 4; ++ks)
#pragma unroll
    for (int n = 0; n < 8; ++n) {
      bf16x8 wf = *(const bf16x8*)(WT + (size_t)(n * 16 + l15) * 128 + ks * 32 + l4 * 8);
      acc[n] = __builtin_amdgcn_mfma_f32_16x16x32_bf16(wf, af[ks], acc[n], 0, 0, 0);
    }

  float alpha = 1.f / (1.f + __expf(-skip[isA ? 0 : 1]));
  float onema = 1.f - alpha;
  float vals[8][4];
  float psum = 0.f, psq = 0.f;
#pragma unroll
  for (int n = 0; n < 8; ++n) {
    int cb = n * 16 + l4 * 4;
    fvec4 b4 = *(const fvec4*)(bias + cb);
    fvec4 xv = *(const fvec4*)(xb + (size_t)rc * 128 + cb);
#pragma unroll
    for (int reg = 0; reg < 4; ++reg) {
      float v = (acc[n][reg] + b4[reg]) * alpha + xv[reg] * onema;
      vals[n][reg] = v;
      psum += v;
      psq = fmaf(v, v, psq);
    }
  }
  psum += __shfl_xor(psum, 16, 64); psq += __shfl_xor(psq, 16, 64);
  psum += __shfl_xor(psum, 32, 64); psq += __shfl_xor(psq, 32, 64);
  float mu = psum * (1.f / 128.f);
  float var = psq * (1.f / 128.f) - mu * mu;
  float is = 1.f / sqrtf(var + 1e-5f);

  if (r < M) {
#pragma unroll
    for (int n = 0; n < 8; ++n) {
      int cb = n * 16 + l4 * 4;
      fvec4 g4 = *(const fvec4*)(g + cb);
      fvec4 bb4 = *(const fvec4*)(bb + cb);
      fvec4 ov;
#pragma unroll
      for (int reg = 0; reg < 4; ++reg)
        ov[reg] = (vals[n][reg] - mu) * is * g4[reg] + bb4[reg];
      *(fvec4*)(o + (size_t)r * 128 + cb) = ov;
    }
  }
}

// ---------------- launch ----------------
extern "C" void kernel_launch(void* const* d_in, const int* in_sizes, int n_in,
                              void* d_out, int out_size, void* d_ws, size_t ws_size,
                              hipStream_t stream)
{
  const float* x_a = (const float*)d_in[0];
  const float* x_b = (const float*)d_in[1];
  const float* ew0 = (const float*)d_in[2];
  const float* ew1 = (const float*)d_in[3];
  const int* src0 = (const int*)d_in[4];
  const int* dst0 = (const int*)d_in[5];
  const int* src1 = (const int*)d_in[6];
  const int* dst1 = (const int*)d_in[7];
  const float* Wk = (const float*)d_in[8];
  const float* bk = (const float*)d_in[9];
  const float* Wq = (const float*)d_in[10];
  const float* bq = (const float*)d_in[11];
  const float* Wv = (const float*)d_in[12];
  const float* bv = (const float*)d_in[13];
  const float* Wa = (const float*)d_in[14];
  const float* ba = (const float*)d_in[15];
  const float* ln_g = (const float*)d_in[16];
  const float* ln_b = (const float*)d_in[17];
  const float* rel_pri = (const float*)d_in[18];
  const float* rel_att = (const float*)d_in[19];
  const float* rel_msg = (const float*)d_in[20];
  const float* skip = (const float*)d_in[21];

  int NA = in_sizes[0] / 128, NB = in_sizes[1] / 128;
  int E0 = in_sizes[2], E1 = in_sizes[3];
  int NMAX = NA > NB ? NA : NB;
  int NM = (NMAX + 255) & ~255;
  int N2 = NA + NB;
  int N2M = (N2 + 255) & ~255;
  int E2 = E0 + E1;
  int E2M = (E2 + 255) & ~255;

  char* wsbase = (char*)d_ws;
  size_t off = 0;
  auto alloc = [&](size_t bytes) { char* p = wsbase + off; off += (bytes + 255) & ~(size_t)255; return p; };
  __bf16* kvb_a = (__bf16*)alloc((size_t)NM * 256 * 2);
  __bf16* kvb_b = (__bf16*)alloc((size_t)NM * 256 * 2);
  __bf16* qd_a  = (__bf16*)alloc((size_t)NM * 128 * 2);
  __bf16* qd_b  = (__bf16*)alloc((size_t)NM * 128 * 2);
  __bf16* agg_a = (__bf16*)alloc((size_t)NM * 128 * 2);
  __bf16* agg_b = (__bf16*)alloc((size_t)NM * 128 * 2);
  __bf16* WkvqT = (__bf16*)alloc(2 * 384 * 128 * 2);
  __bf16* WaT   = (__bf16*)alloc(2 * 128 * 128 * 2);
  float* bkvq   = (float*)alloc(2 * 384 * 4);
  int* deg      = (int*)alloc((size_t)N2M * 4);
  int* row_st   = (int*)alloc((size_t)N2M * 4);
  int* cur      = (int*)alloc((size_t)N2M * 4);
  int* partial  = (int*)alloc(1024 * 4);
  int* pscan    = (int*)alloc(1024 * 4);
  int* sidx     = (int*)alloc((size_t)E2M * 4);
  float* ewc    = (float*)alloc((size_t)E2M * 4);

  float* outf = (float*)d_out;
  dim3 b256(256);
  auto cdiv = [](int a, int b) { return (unsigned)((a + b - 1) / b); };

  // weights prep
  fuse_w<<<dim3(129, 2), b256, 0, stream>>>(Wk, bk, Wv, bv, rel_att, rel_msg, WkvqT, bkvq);
  cvt_wT<<<dim3(128, 2, 2), 128, 0, stream>>>(Wq, bq, Wa, WkvqT, WaT, bkvq);

  // CSR for both relations, concatenated [NB | NA]
  int NP = (N2 + 1023) / 1024;
  fzero<<<64, b256, 0, stream>>>((float*)deg, N2);
  csr_count2<<<cdiv(E2, 256), b256, 0, stream>>>(dst0, E0, dst1, E1, deg, NB);
  csr_partial<<<NP, b256, 0, stream>>>(deg, N2, partial);
  csr_scan_partials<<<1, 64, 0, stream>>>(partial, pscan, NP);
  csr_scan_chunk<<<NP, b256, 0, stream>>>(deg, pscan, row_st, cur, N2);
  csr_scatter2<<<cdiv(E2, 256), b256, 0, stream>>>(dst0, src0, ew0, E0,
                                                   dst1, src1, ew1, E1,
                                                   cur, sidx, ewc, NB);

  // ---- fused projections: persistent grid over both node types ----
  int nta = cdiv(NA, 64), ntb = cdiv(NB, 64);
  int ntiles = nta + ntb;
  int ggrid = ntiles < 1024 ? ntiles : 1024;   // 4 blocks/CU, all resident
  gemm_kvq<<<ggrid, b256, 0, stream>>>(x_a, NA, x_b, NB, WkvqT, bkvq,
                                       kvb_a, qd_a, kvb_b, qd_b, nta, ntiles);

  // ---- attention: both relations, one dispatch ----
  hgt_dst<<<cdiv(N2, 4), b256, 0, stream>>>(kvb_a, qd_b, kvb_b, qd_a,
                                            row_st, deg, sidx, ewc, rel_pri,
                                            agg_b, agg_a, NB, N2);

  // ---- fused Wa projection + skip + LayerNorm: both types, one dispatch ----
  wa_ln<<<nta + ntb, b256, 0, stream>>>(agg_a, agg_b, WaT, ba, x_a, x_b,
                                        ln_g, ln_b, skip, outf, NA, NB, nta);
}